// Round 25
// baseline (458.844 us; speedup 1.0000x reference)
//
#include <hip/hip_runtime.h>
#include <math.h>

// R25 = MEASUREMENT ROUND. R19 pipeline with x16 internal repetition per
// kernel (idempotent). Each kernel's dur exceeds the ~39us harness fills ->
// top-5 reveals per-kernel times (divide by 16). Decomposes the 43us budget
// that 24 rounds of modeling failed to attribute.

// Problem constants (fixed by harness)
#define NN   128
#define TT   1024
#define SS   1024
#define H1D  512
#define H2D  128
#define OUTD 8
#define KQN  8
#define REPS 16

// NUFFT constants (validated R9-R24, absmax 0.0039)
#define MR    2048
#define WHALF 5
#define ALPHA 0.3702402f           // pi/sqrt(72)
#define BETA  6.35556e-6f          // pi^2/(ALPHA*MR^2)
#define DSCALE 0.3432943f          // sqrt(ALPHA/pi)

// ws layout in floats
#define OFF_SUBT 0                          // [128 n][512 q][4 r] float2
#define OFF_P1   (NN*512*4*2)               // P1 [8 kq][128 n][512 j]
// end: OFF_P1 + 8*128*512 = 1048576

__device__ __forceinline__ float cos_rev(float r) { return __builtin_amdgcn_cosf(r); } // cos(2*pi*r)
__device__ __forceinline__ float sin_rev(float r) { return __builtin_amdgcn_sinf(r); } // sin(2*pi*r)

__device__ __forceinline__ float wave_sum(float v) {
#pragma unroll
    for (int off = 32; off > 0; off >>= 1) v += __shfl_xor(v, off, 64);
    return v;
}

// ---------------------------------------------------------------------------
// Kernel 1: residue-spread + sub-FFT (R19 verbatim body) x REPS
// ---------------------------------------------------------------------------
__global__ __launch_bounds__(256) void k_sf(const float* __restrict__ inp,
                                            float* __restrict__ ws) {
    const int r   = blockIdx.x;    // 0..3
    const int n   = blockIdx.y;    // 0..127
    const int tid = threadIdx.x;   // 0..255

    __shared__ float2 Ag[512];
    __shared__ float2 Bg[512];

    for (int rep = 0; rep < REPS; ++rep) {
        __syncthreads();
        Ag[tid] = make_float2(0.f, 0.f);
        Ag[tid + 256] = make_float2(0.f, 0.f);
        __syncthreads();

        const float* row = inp + (size_t)n * TT * 3;
#pragma unroll
        for (int pp = 0; pp < 4; ++pp) {
            const int t = pp * 256 + tid;
            const float x  = row[t * 3 + 0];
            const float d  = row[t * 3 + 2];
            const float df = d - floorf(d);            // exact for |d| < 2^23
            const float p512 = 512.0f * df;            // exact (pow2 scale)
            const float r512 = p512 - floorf(p512);
            const float cre = x * cos_rev(r512);
            const float cim = -x * sin_rev(r512);
            const float z  = df * 2048.0f;             // [0,2048)
            const int   j0 = (int)z;
            const float dl = z - (float)j0;
            const int k0 = (r + 5 - j0 + 2048) & 3;
#pragma unroll
            for (int i = 0; i < 3; ++i) {
                const int   k = k0 + 4 * i;
                const float u = dl - (float)(k - WHALF);
                const float w = __expf(-ALPHA * u * u);
                const int  gi = (j0 + k - WHALF) & (MR - 1);
                const int   q = gi >> 2;               // gi == r (mod 4)
                atomicAdd(&Ag[q].x, w * cre);
                atomicAdd(&Ag[q].y, w * cim);
            }
        }
        __syncthreads();

        // Stockham radix-2, N=512, 9 stages (validated)
        float2* src = Ag;
        float2* dst = Bg;
#pragma unroll
        for (int s = 0; s < 9; ++s) {
            const int   m    = 1 << s;
            const float invl = 1.0f / (float)(512 >> s);
            const int tau = tid;
            const int j   = tau >> s;
            const float rr = (float)j * invl;
            const float cv = cos_rev(rr), sv = sin_rev(rr);  // w = cv - i*sv
            const float2 a = src[tau];
            const float2 b = src[tau + 256];
            const int o = tau + (tau & ~(m - 1));
            dst[o] = make_float2(a.x + b.x, a.y + b.y);
            const float dr = a.x - b.x, di = a.y - b.y;
            dst[o + m] = make_float2(fmaf(di, sv, dr * cv),
                                     fmaf(di, cv, -dr * sv));
            __syncthreads();
            float2* tmp = src; src = dst; dst = tmp;
        }

        float2* SUBT = (float2*)(ws + OFF_SUBT);
        SUBT[((size_t)n * 512 + tid)       * 4 + r] = src[tid];
        SUBT[((size_t)n * 512 + tid + 256) * 4 + r] = src[tid + 256];
    }
}

// ---------------------------------------------------------------------------
// Kernel 2: comb + split-K GEMM (R19 verbatim body) x REPS
// ---------------------------------------------------------------------------
__global__ __launch_bounds__(256) void k_cl1p(const float* __restrict__ W1,
                                              float* __restrict__ ws) {
    const int kq = blockIdx.x;   // 0..7
    const int jq = blockIdx.y;   // 0..3
    const int nb = blockIdx.z;   // 0..15
    const int tid = threadIdx.x;

    __shared__ float4 Al[8][32];

    for (int rep = 0; rep < REPS; ++rep) {
        __syncthreads();
        float* Alf = (float*)Al;
        const float2* SUBT = (const float2*)(ws + OFF_SUBT);
#pragma unroll
        for (int i = 0; i < 4; ++i) {
            const int e    = i * 256 + tid;        // 0..1023
            const int rown = e >> 7;               // 0..7
            const int kk   = e & 127;
            const int n    = nb * 8 + rown;
            const int ss   = kq * 128 + kk;
            const int k    = (ss + 1536) & (MR - 1);
            const int km   = ss & 511;
            const float2* F = SUBT + ((size_t)n * 512 + km) * 4;
            float2 X = F[0];                       // r=0: w=1
            const float f1 = (float)k * (1.0f / 2048.0f);   // exact
#pragma unroll
            for (int rr = 1; rr < 4; ++rr) {
                const float2 Fr = F[rr];
                const float fr = (float)rr * f1;
                const float ff = fr - floorf(fr);  // exact
                const float cv = cos_rev(ff), sv = sin_rev(ff);
                X.x = fmaf(Fr.x, cv, fmaf(Fr.y, sv, X.x));
                X.y = fmaf(Fr.y, cv, fmaf(-Fr.x, sv, X.y));
            }
            const int sp = ss - 512;
            const float D = DSCALE * __expf(BETA * (float)(sp * sp));
            Alf[e] = sqrtf(fmaf(X.x, X.x, X.y * X.y)) * D;
        }
        __syncthreads();

        // R19-verbatim l1p GEMM body
        const int jl = tid & 127, ng = tid >> 7;
        const int j = jq * 128 + jl;
        const float4* W1v = (const float4*)W1;
        float a0 = 0.f, a1 = 0.f, a2 = 0.f, a3 = 0.f;
#pragma unroll 4
        for (int k4 = 0; k4 < 32; ++k4) {
            const float4 w  = W1v[(size_t)j * 256 + kq * 32 + k4];
            const float4 x0 = Al[ng * 4 + 0][k4];
            const float4 x1 = Al[ng * 4 + 1][k4];
            const float4 x2 = Al[ng * 4 + 2][k4];
            const float4 x3 = Al[ng * 4 + 3][k4];
            a0 = fmaf(x0.x, w.x, fmaf(x0.y, w.y, fmaf(x0.z, w.z, fmaf(x0.w, w.w, a0))));
            a1 = fmaf(x1.x, w.x, fmaf(x1.y, w.y, fmaf(x1.z, w.z, fmaf(x1.w, w.w, a1))));
            a2 = fmaf(x2.x, w.x, fmaf(x2.y, w.y, fmaf(x2.z, w.z, fmaf(x2.w, w.w, a2))));
            a3 = fmaf(x3.x, w.x, fmaf(x3.y, w.y, fmaf(x3.z, w.z, fmaf(x3.w, w.w, a3))));
        }
        float* P1 = ws + OFF_P1;
        const float acc[4] = {a0, a1, a2, a3};
#pragma unroll
        for (int i = 0; i < 4; ++i)
            P1[((size_t)(kq * NN + nb * 8 + ng * 4 + i)) * H1D + j] = acc[i];
    }
}

// ---------------------------------------------------------------------------
// Kernel 3: MLP tail (R19 verbatim body) x REPS
// ---------------------------------------------------------------------------
__global__ __launch_bounds__(1024) void k_mlp(const float* __restrict__ b1,
                                              const float* __restrict__ W2,
                                              const float* __restrict__ b2,
                                              const float* __restrict__ W3,
                                              const float* __restrict__ b3,
                                              const float* __restrict__ ws,
                                              float* __restrict__ out) {
    const int n   = blockIdx.x;
    const int tid = threadIdx.x;
    const int wid = tid >> 6, lane = tid & 63;

    __shared__ float h1L[H1D];
    __shared__ float h2L[H2D];

    for (int rep = 0; rep < REPS; ++rep) {
        __syncthreads();
        if (tid < H1D) {
            const int j = tid;
            float s = b1[j];
#pragma unroll
            for (int kq = 0; kq < KQN; ++kq)
                s += ws[OFF_P1 + ((size_t)kq * NN + n) * H1D + j];
            h1L[j] = 1.0f / (1.0f + __expf(-s));
        }
        __syncthreads();

        {
            const float4* H1v = (const float4*)h1L;
            const float4 ha = H1v[lane], hb = H1v[64 + lane];
#pragma unroll
            for (int q = 0; q < 8; ++q) {
                const int j = wid * 8 + q;
                const float4* W2v = (const float4*)W2 + (size_t)j * 128;
                const float4 wa = W2v[lane], wb = W2v[64 + lane];
                float a = fmaf(wa.x, ha.x, fmaf(wa.y, ha.y, fmaf(wa.z, ha.z, wa.w * ha.w)));
                a = fmaf(wb.x, hb.x, fmaf(wb.y, hb.y, fmaf(wb.z, hb.z, fmaf(wb.w, hb.w, a))));
                a = wave_sum(a);
                if (lane == 0) h2L[j] = 1.0f / (1.0f + __expf(-(a + b2[j])));
            }
        }
        __syncthreads();

        if (wid < OUTD) {
            const float2 w = ((const float2*)W3)[wid * 64 + lane];
            const float2 h = ((const float2*)h2L)[lane];
            float a = fmaf(w.x, h.x, w.y * h.y);
            a = wave_sum(a);
            if (lane == 0) out[n * OUTD + wid] = a + b3[wid];
        }
    }
}

extern "C" void kernel_launch(void* const* d_in, const int* in_sizes, int n_in,
                              void* d_out, int out_size, void* d_ws, size_t ws_size,
                              hipStream_t stream) {
    (void)in_sizes; (void)n_in; (void)out_size; (void)ws_size;
    const float* inp = (const float*)d_in[0];
    const float* W1  = (const float*)d_in[1];
    const float* b1  = (const float*)d_in[2];
    const float* W2  = (const float*)d_in[3];
    const float* b2  = (const float*)d_in[4];
    const float* W3  = (const float*)d_in[5];
    const float* b3  = (const float*)d_in[6];
    float* out = (float*)d_out;
    float* ws  = (float*)d_ws;

    k_sf  <<<dim3(4, NN),    dim3(256),  0, stream>>>(inp, ws);
    k_cl1p<<<dim3(8, 4, 16), dim3(256),  0, stream>>>(W1, ws);
    k_mlp <<<dim3(NN),       dim3(1024), 0, stream>>>(b1, W2, b2, W3, b3, ws, out);
}

// Round 27
// 36.197 us; speedup vs baseline: 12.6762x; 12.6762x over previous
//
#include <hip/hip_runtime.h>
#include <math.h>

// Problem constants (fixed by harness)
#define NN   128
#define TT   1024
#define SS   1024
#define H1D  512
#define H2D  128
#define OUTD 8
#define KQN  8      // layer-1 split-K chunks

// NUFFT constants. R26: Gaussian width 12 -> 8 (alpha = pi/sqrt(32)), exactly
// 2 taps per residue. Error e^-8.9 ~ 1.4e-4 rel (~4e-3 abs on freq) — within
// the bf16-output budget (threshold 0.0223 = 5.7 ulp; we sit at 1 ulp).
#define MR    2048
#define WHALF 3                    // window offsets k-3, k=0..7
#define ALPHA 0.5553604f           // pi/sqrt(32)
#define BETA  4.2368e-6f           // pi^2/(ALPHA*MR^2)
#define DSCALE 0.4204754f          // sqrt(ALPHA/pi)

// ws layout in floats
#define OFF_SUBT 0                          // [128 n][512 q][4 r] float2
#define OFF_P1   (NN*512*4*2)               // P1 [8 kq][128 n][512 j]
// end: OFF_P1 + 8*128*512 = 1048576

__device__ __forceinline__ float cos_rev(float r) { return __builtin_amdgcn_cosf(r); } // cos(2*pi*r)
__device__ __forceinline__ float sin_rev(float r) { return __builtin_amdgcn_sinf(r); } // sin(2*pi*r)

__device__ __forceinline__ float wave_sum(float v) {
#pragma unroll
    for (int off = 32; off > 0; off >>= 1) v += __shfl_xor(v, off, 64);
    return v;
}

// ---------------------------------------------------------------------------
// Kernel 1: FUSED residue-spread + 512-pt sub-FFT.
// R26 changes vs R19 (17.2us measured, VALUBusy 1.4% = latency-stalled):
//  (a) 512 threads/block (4096 waves = 4/SIMD, 2 blocks/CU) — more
//      independent barrier chains per SIMD to hide LDS/barrier latency.
//  (b) w=8 Gaussian: exactly 2 taps per residue (k0, k0+4) — 33% less
//      spread work. FFT math bit-identical (tid<256 compute, barriers
//      hoisted outside the conditional).
// ---------------------------------------------------------------------------
__global__ __launch_bounds__(512) void k_sf(const float* __restrict__ inp,
                                            float* __restrict__ ws) {
    const int r   = blockIdx.x;    // 0..3
    const int n   = blockIdx.y;    // 0..127
    const int tid = threadIdx.x;   // 0..511

    __shared__ float2 Ag[512];     // 4 KB
    __shared__ float2 Bg[512];     // 4 KB

    Ag[tid] = make_float2(0.f, 0.f);
    __syncthreads();

    const float* row = inp + (size_t)n * TT * 3;
#pragma unroll
    for (int pp = 0; pp < 2; ++pp) {
        const int t = pp * 512 + tid;
        const float x  = row[t * 3 + 0];
        const float d  = row[t * 3 + 2];
        const float df = d - floorf(d);            // exact for |d| < 2^23
        const float p512 = 512.0f * df;            // exact (pow2 scale)
        const float r512 = p512 - floorf(p512);
        const float cre = x * cos_rev(r512);
        const float cim = -x * sin_rev(r512);
        const float z  = df * 2048.0f;             // [0,2048)
        const int   j0 = (int)z;
        const float dl = z - (float)j0;
        const int k0 = (r + WHALF - j0 + 2048) & 3;
#pragma unroll
        for (int i = 0; i < 2; ++i) {
            const int   k = k0 + 4 * i;
            const float u = dl - (float)(k - WHALF);
            const float w = __expf(-ALPHA * u * u);
            const int  gi = (j0 + k - WHALF) & (MR - 1);
            const int   q = gi >> 2;               // gi == r (mod 4)
            atomicAdd(&Ag[q].x, w * cre);
            atomicAdd(&Ag[q].y, w * cim);
        }
    }
    __syncthreads();

    // Stockham radix-2, N=512, 9 stages (R19-verbatim math on tid<256;
    // barriers outside the conditional so all 512 threads participate).
    float2* src = Ag;
    float2* dst = Bg;
#pragma unroll
    for (int s = 0; s < 9; ++s) {
        if (tid < 256) {
            const int   m    = 1 << s;
            const float invl = 1.0f / (float)(512 >> s);
            const int tau = tid;
            const int j   = tau >> s;
            const float rr = (float)j * invl;
            const float cv = cos_rev(rr), sv = sin_rev(rr);  // w = cv - i*sv
            const float2 a = src[tau];
            const float2 b = src[tau + 256];
            const int o = tau + (tau & ~(m - 1));
            dst[o] = make_float2(a.x + b.x, a.y + b.y);
            const float dr = a.x - b.x, di = a.y - b.y;
            dst[o + m] = make_float2(fmaf(di, sv, dr * cv),
                                     fmaf(di, cv, -dr * sv));
        }
        __syncthreads();
        float2* tmp = src; src = dst; dst = tmp;
    }

    float2* SUBT = (float2*)(ws + OFF_SUBT);
    SUBT[((size_t)n * 512 + tid) * 4 + r] = src[tid];
}

// ---------------------------------------------------------------------------
// Kernel 2: FUSED radix-4 combine+deconvolve+magnitude -> LDS tile -> l1p GEMM.
// R19 verbatim (DSCALE/BETA pick up the w=8 constants automatically).
// Grid (8 kq, 4 jq, 16 nb) = 512 blocks x 256 thr.
// ---------------------------------------------------------------------------
__global__ __launch_bounds__(256) void k_cl1p(const float* __restrict__ W1,
                                              float* __restrict__ ws) {
    const int kq = blockIdx.x;   // 0..7
    const int jq = blockIdx.y;   // 0..3
    const int nb = blockIdx.z;   // 0..15
    const int tid = threadIdx.x;

    __shared__ float4 Al[8][32];  // 8 n-rows x 128 k
    float* Alf = (float*)Al;
    const float2* SUBT = (const float2*)(ws + OFF_SUBT);
#pragma unroll
    for (int i = 0; i < 4; ++i) {
        const int e    = i * 256 + tid;        // 0..1023
        const int rown = e >> 7;               // 0..7
        const int kk   = e & 127;
        const int n    = nb * 8 + rown;
        const int ss   = kq * 128 + kk;
        const int k    = (ss + 1536) & (MR - 1);
        const int km   = ss & 511;
        const float2* F = SUBT + ((size_t)n * 512 + km) * 4;
        float2 X = F[0];                       // r=0: w=1
        const float f1 = (float)k * (1.0f / 2048.0f);   // exact
#pragma unroll
        for (int rr = 1; rr < 4; ++rr) {
            const float2 Fr = F[rr];
            const float fr = (float)rr * f1;
            const float ff = fr - floorf(fr);  // exact
            const float cv = cos_rev(ff), sv = sin_rev(ff);  // w = cv - i*sv
            X.x = fmaf(Fr.x, cv, fmaf(Fr.y, sv, X.x));
            X.y = fmaf(Fr.y, cv, fmaf(-Fr.x, sv, X.y));
        }
        const int sp = ss - 512;
        const float D = DSCALE * __expf(BETA * (float)(sp * sp));
        Alf[e] = sqrtf(fmaf(X.x, X.x, X.y * X.y)) * D;
    }
    __syncthreads();

    // R19-verbatim l1p GEMM body
    const int jl = tid & 127, ng = tid >> 7;
    const int j = jq * 128 + jl;
    const float4* W1v = (const float4*)W1;
    float a0 = 0.f, a1 = 0.f, a2 = 0.f, a3 = 0.f;
#pragma unroll 4
    for (int k4 = 0; k4 < 32; ++k4) {
        const float4 w  = W1v[(size_t)j * 256 + kq * 32 + k4];
        const float4 x0 = Al[ng * 4 + 0][k4];
        const float4 x1 = Al[ng * 4 + 1][k4];
        const float4 x2 = Al[ng * 4 + 2][k4];
        const float4 x3 = Al[ng * 4 + 3][k4];
        a0 = fmaf(x0.x, w.x, fmaf(x0.y, w.y, fmaf(x0.z, w.z, fmaf(x0.w, w.w, a0))));
        a1 = fmaf(x1.x, w.x, fmaf(x1.y, w.y, fmaf(x1.z, w.z, fmaf(x1.w, w.w, a1))));
        a2 = fmaf(x2.x, w.x, fmaf(x2.y, w.y, fmaf(x2.z, w.z, fmaf(x2.w, w.w, a2))));
        a3 = fmaf(x3.x, w.x, fmaf(x3.y, w.y, fmaf(x3.z, w.z, fmaf(x3.w, w.w, a3))));
    }
    float* P1 = ws + OFF_P1;
    const float acc[4] = {a0, a1, a2, a3};
#pragma unroll
    for (int i = 0; i < 4; ++i)
        P1[((size_t)(kq * NN + nb * 8 + ng * 4 + i)) * H1D + j] = acc[i];
}

// ---------------------------------------------------------------------------
// Kernel 3: FUSED MLP tail per batch n (l1c + l2 + l3) — R19 verbatim.
// 128 blocks x 1024 thr.
// ---------------------------------------------------------------------------
__global__ __launch_bounds__(1024) void k_mlp(const float* __restrict__ b1,
                                              const float* __restrict__ W2,
                                              const float* __restrict__ b2,
                                              const float* __restrict__ W3,
                                              const float* __restrict__ b3,
                                              const float* __restrict__ ws,
                                              float* __restrict__ out) {
    const int n   = blockIdx.x;
    const int tid = threadIdx.x;
    const int wid = tid >> 6, lane = tid & 63;

    __shared__ float h1L[H1D];
    __shared__ float h2L[H2D];

    if (tid < H1D) {
        const int j = tid;
        float s = b1[j];
#pragma unroll
        for (int kq = 0; kq < KQN; ++kq)
            s += ws[OFF_P1 + ((size_t)kq * NN + n) * H1D + j];
        h1L[j] = 1.0f / (1.0f + __expf(-s));
    }
    __syncthreads();

    // layer 2: wave wid handles j = wid*8 .. wid*8+7
    {
        const float4* H1v = (const float4*)h1L;
        const float4 ha = H1v[lane], hb = H1v[64 + lane];
#pragma unroll
        for (int q = 0; q < 8; ++q) {
            const int j = wid * 8 + q;
            const float4* W2v = (const float4*)W2 + (size_t)j * 128;
            const float4 wa = W2v[lane], wb = W2v[64 + lane];
            float a = fmaf(wa.x, ha.x, fmaf(wa.y, ha.y, fmaf(wa.z, ha.z, wa.w * ha.w)));
            a = fmaf(wb.x, hb.x, fmaf(wb.y, hb.y, fmaf(wb.z, hb.z, fmaf(wb.w, hb.w, a))));
            a = wave_sum(a);
            if (lane == 0) h2L[j] = 1.0f / (1.0f + __expf(-(a + b2[j])));
        }
    }
    __syncthreads();

    // layer 3: waves 0..7, one output each
    if (wid < OUTD) {
        const float2 w = ((const float2*)W3)[wid * 64 + lane];
        const float2 h = ((const float2*)h2L)[lane];
        float a = fmaf(w.x, h.x, w.y * h.y);
        a = wave_sum(a);
        if (lane == 0) out[n * OUTD + wid] = a + b3[wid];
    }
}

extern "C" void kernel_launch(void* const* d_in, const int* in_sizes, int n_in,
                              void* d_out, int out_size, void* d_ws, size_t ws_size,
                              hipStream_t stream) {
    (void)in_sizes; (void)n_in; (void)out_size; (void)ws_size;
    const float* inp = (const float*)d_in[0];
    const float* W1  = (const float*)d_in[1];
    const float* b1  = (const float*)d_in[2];
    const float* W2  = (const float*)d_in[3];
    const float* b2  = (const float*)d_in[4];
    const float* W3  = (const float*)d_in[5];
    const float* b3  = (const float*)d_in[6];
    float* out = (float*)d_out;
    float* ws  = (float*)d_ws;

    k_sf  <<<dim3(4, NN),    dim3(512),  0, stream>>>(inp, ws);
    k_cl1p<<<dim3(8, 4, 16), dim3(256),  0, stream>>>(W1, ws);
    k_mlp <<<dim3(NN),       dim3(1024), 0, stream>>>(b1, W2, b2, W3, b3, ws, out);
}